// Round 4
// baseline (870.783 us; speedup 1.0000x reference)
//
#include <hip/hip_runtime.h>

// Encoder: embed -> fused 2-dir input GEMMs (bf16 MFMA, B panel staged ONCE per block in
//          padded LDS, barrier-free K-loop, n-major G layout => coalesced stores)
//          -> 4x LSTM scan (SINGLE-WG recurrence, 1024-thr WG = 16 waves @ 4 waves/SIMD,
//             Whh as i8 row-scaled register-resident B-frags (AGPR), h double-buffered in
//             LDS, ONE barrier/step, VMEM software-pipelined one full step)
//          -> co-attention + output head.
// Sizes: V=100000 E=300 H=256 OUT=3 B=128 LS=128 LT=8

typedef unsigned short u16;
typedef unsigned long long u64;
typedef float f32x4 __attribute__((ext_vector_type(4)));
typedef int   i32x4 __attribute__((ext_vector_type(4)));
typedef short bf16x8 __attribute__((ext_vector_type(8)));

#define KP 320   // E=300 padded to mult of 32
#define KPL 328  // LDS leading dim (u16): 656B row stride -> even bank-slot coverage, 16B aligned
#define FH 1024  // 4*H
#define HH 256   // H

struct Ptr4 { const float* p[4]; };

static __device__ __forceinline__ u16 f2bf(float f) {
    unsigned int u = __float_as_uint(f);
    u += 0x7FFFu + ((u >> 16) & 1u);          // RNE
    return (u16)(u >> 16);
}
static __device__ __forceinline__ float bf2f(u16 s) {
    return __uint_as_float((unsigned int)s << 16);
}
static __device__ __forceinline__ float sigm(float x) {
    return __builtin_amdgcn_rcpf(1.0f + __expf(-x));
}
static __device__ __forceinline__ float tanh_(float x) {
    return 1.0f - 2.0f * __builtin_amdgcn_rcpf(1.0f + __expf(2.0f * x));
}

// ---------------------------------------------------------------- embedding
__global__ void embed_kernel(const int* __restrict__ sen, const int* __restrict__ tgt,
                             const float* __restrict__ emb,
                             u16* __restrict__ Xs, u16* __restrict__ Xt)
{
    int row = blockIdx.x;
    int tok; u16* dst;
    if (row < 16384) { tok = sen[row]; dst = Xs + (size_t)row * KP; }
    else             { tok = tgt[row - 16384]; dst = Xt + (size_t)(row - 16384) * KP; }
    const float* src = emb + (size_t)tok * 300;
    for (int k = threadIdx.x; k < KP; k += blockDim.x) {
        float v = (k < 300 && tok != 0) ? src[k] : 0.0f;   // padding_idx=0
        dst[k] = f2bf(v);
    }
}

// ---------------------------------------------------------------- weight prep (all 4 dirs)
__global__ __launch_bounds__(256) void prep_weights_kernel(
    Ptr4 Wih, Ptr4 bih, Ptr4 bhh, u16* __restrict__ WihB, float* __restrict__ biasB)
{
    int dir = blockIdx.y;
    int idx = blockIdx.x * 256 + threadIdx.x;
    if (idx < FH * KP) {
        int row = idx / KP, k = idx - row * KP;
        WihB[(size_t)dir * FH * KP + idx] = (k < 300) ? f2bf(Wih.p[dir][row * 300 + k]) : (u16)0;
    }
    if (idx < FH) biasB[dir * FH + idx] = bih.p[dir][idx] + bhh.p[dir][idx];
}

// ---------------------------------------------------------------- Whh -> i8 row-scaled (all dirs)
__global__ __launch_bounds__(64) void whh_quant_kernel(
    Ptr4 Whh, char* __restrict__ Wq, float* __restrict__ wdq)
{
    int dir = blockIdx.y, row = blockIdx.x, tid = threadIdx.x;
    const float* src = Whh.p[dir] + (size_t)row * HH;
    float m = 0.0f;
    for (int k = tid; k < HH; k += 64) m = fmaxf(m, fabsf(src[k]));
    for (int off = 32; off; off >>= 1) m = fmaxf(m, __shfl_down(m, off));
    m = __shfl(m, 0);
    float qs = (m > 0.0f) ? 127.0f / m : 0.0f;
    char* dst = Wq + (size_t)dir * FH * HH + (size_t)row * HH;
    for (int k = tid; k < HH; k += 64) dst[k] = (char)(int)rintf(src[k] * qs);
    if (tid == 0) wdq[dir * FH + row] = (m > 0.0f) ? m / (127.0f * 127.0f) : 0.0f;
}

// ---------------------------------------------------------------- input GEMM (fused dir-pair)
// One launch covers TWO directions: W has 2048 rows (dir-major), N=2048, NB=32 n-blocks.
// 64x64 tile per 256-thr block. The 64-row B panel (full K=320) is staged ONCE into
// padded LDS (KPL=328: 656B row stride -> b128 reads cover all 8 bank-slots evenly =
// conflict-free), then the K-loop runs barrier-free: A streamed from global (L2-resident
// across the 32 n-blocks of the same m-tile via XCD swizzle), B frags from LDS.
// G layout: n-major [m][gate*256+unit] => stores are contiguous 32B chunks per quad
// (the old gate-interleaved layout stored 2B at 8B stride = 25% sector efficiency,
// amplifying the 67MB G-write ~4x).
__global__ __launch_bounds__(256) void input_gemm_kernel(
    const u16* __restrict__ X, const u16* __restrict__ W,
    const float* __restrict__ bias, u16* __restrict__ G, size_t dirStride)
{
    __shared__ u16 Bs[64][KPL];

    int nwg = gridDim.x;                       // multiple of 8
    int cpx = nwg >> 3;
    int wid = ((int)blockIdx.x & 7) * cpx + ((int)blockIdx.x >> 3);
    int nblk = wid & 31;                       // NB = 32 (N = 2048)
    int mblk = wid >> 5;

    int tid = threadIdx.x;
    int wave = tid >> 6, lane = tid & 63;
    int r = lane & 15, quad = lane >> 4;
    int m0 = mblk * 64 + wave * 16;
    int n0 = nblk * 64;

    // ---- stage B panel: 64 rows x 320 cols bf16 (2560 16B-chunks, 10 rounds)
#pragma unroll
    for (int it = 0; it < 10; ++it) {
        int idx = it * 256 + tid;              // 64*40 chunks of 8 u16
        int row = idx / 40, c = idx - row * 40;
        bf16x8 v = *(const bf16x8*)(W + (size_t)(n0 + row) * KP + c * 8);
        *(bf16x8*)&Bs[row][c * 8] = v;
    }
    __syncthreads();

    // ---- barrier-free K loop
    const u16* xr = X + (size_t)(m0 + r) * KP + quad * 8;
    f32x4 acc[4] = {};
#pragma unroll
    for (int k0 = 0; k0 < KP; k0 += 32) {
        bf16x8 a = *(const bf16x8*)(xr + k0);
#pragma unroll
        for (int j = 0; j < 4; ++j) {
            bf16x8 b = *(const bf16x8*)&Bs[j * 16 + r][k0 + quad * 8];
            acc[j] = __builtin_amdgcn_mfma_f32_16x16x32_bf16(a, b, acc[j], 0, 0, 0);
        }
    }

    // ---- epilogue: bias + bf16, coalesced n-major stores
#pragma unroll
    for (int j = 0; j < 4; ++j)
#pragma unroll
        for (int reg = 0; reg < 4; ++reg) {
            int m = m0 + quad * 4 + reg;
            int n = n0 + j * 16 + r;           // global col in [0,2048)
            int dirb = n >> 10, nn = n & 1023;
            G[(size_t)dirb * dirStride + (size_t)m * FH + nn]
                = f2bf(acc[j][reg] + bias[n]);
        }
}

// ---------------------------------------------------------------- LSTM scan
// 32 WGs x 1024 thr (16 waves; 1024-thr WG forces 4 waves/SIMD => 128-reg cap).
// dir = bx>>3, batch chunk = (bx&7)*16. ONE WG holds the entire direction recurrence
// for its 16 batches. Wave w owns units [w*16,w*16+16) x 4 gates = 64 Whh rows:
// Bq[4][8] u64 = 64 regs/lane of i8 B-frags (AGPR; R2/R3 showed VGPR=64 => Bq in AGPRs).
// VMEM software-pipelined one full step: gv(s+1) prefetched + h(s-1) stored at the TOP
// of step s so the vmcnt(0)-before-s_barrier drain is free (R3: 360->310us).
// G is n-major => gv is 16 coalesced scalar u16 loads (2B x 16 consecutive lanes = 32B).
// mfma_i32_16x16x32_i8: A lane(m=l&15,k=quad*8+j), B lane(n=l&15,k=quad*8+j),
// D lane(col=l&15,row=quad*4+reg) — all 4 gates of a unit land in one lane.
__global__ __launch_bounds__(1024, 1) void lstm_scan_kernel(
    const char*  __restrict__ WqB,   // [4][1024][256] i8
    const float* __restrict__ wdq,   // [4][1024] dequant scales
    const u16*   __restrict__ Gs,    // [2][16384][1024] bf16 (n-major, bias folded)
    const u16*   __restrict__ Gt,    // [2][1024][1024] bf16
    float* __restrict__ senH,        // [128][128][512]
    float* __restrict__ tgtH)        // [128][8][512]
{
    const int bx  = blockIdx.x;
    const int dir = bx >> 3;
    const int b0  = (bx & 7) << 4;
    const int T   = (dir < 2) ? 128 : 8;
    const int rev = dir & 1;

    const char* Wq = WqB + (size_t)dir * FH * HH;
    const u16*  G  = (dir < 2) ? (Gs + (size_t)dir * 16384 * FH)
                               : (Gt + (size_t)(dir - 2) * 1024 * FH);
    float* Hout = (dir < 2) ? senH : tgtH;
    const int hofs = rev ? 256 : 0;

    const int tid  = threadIdx.x;
    const int w    = tid >> 6, lane = tid & 63;
    const int r    = lane & 15, quad = lane >> 4;
    const int u    = w * 16 + r;     // this lane's unit

    __shared__ char hb8[2][16][272]; // h as i8, double-buffered (A-operand source)

    // ---- Whh i8 B-frags into registers (persist across all steps)
    // Bq[g][kt]: row = g*256 + u, k-slice = kt*32 + quad*8
    u64 Bq[4][8];
    float dqv[4];
#pragma unroll
    for (int g = 0; g < 4; ++g) {
        int row = g * 256 + u;
        dqv[g] = wdq[dir * FH + row];
#pragma unroll
        for (int kt = 0; kt < 8; ++kt)
            Bq[g][kt] = *(const u64*)(Wq + ((size_t)row << 8) + kt * 32 + quad * 8);
    }

    // ---- zero h(-1) (buffer 0; buffer 1 is written before first read)
    for (int i = tid; i < 2 * 16 * 272; i += 1024) (&hb8[0][0][0])[i] = 0;
    __syncthreads();

    float c[4] = {};      // cell state per batch-row reg
    float hreg[4] = {};   // h(s-1), stored to Hout one step late
    int tprev = 0;

    // ---- prologue: pregates for step 0
    u16 gvA[4][4], gvB[4][4];     // [reg][gate]
    {
        const int t0 = rev ? (T - 1) : 0;
#pragma unroll
        for (int reg = 0; reg < 4; ++reg)
#pragma unroll
            for (int g = 0; g < 4; ++g)
                gvA[reg][g] = G[((size_t)(b0 + quad * 4 + reg) * T + t0) * FH
                                + g * 256 + u];
    }

    // One step: prefetch gv(next) + store h(prev) FIRST (retire under MFMA+gates),
    // then MFMA from hb8[cur], then gates -> hreg + hb8[cur^1], then barrier.
    auto body = [&](int cur, u16 (&gvU)[4][4], u16 (&gvP)[4][4],
                    int t, int tn, int doStore) {
#pragma unroll
        for (int reg = 0; reg < 4; ++reg)
#pragma unroll
            for (int g = 0; g < 4; ++g)
                gvP[reg][g] = G[((size_t)(b0 + quad * 4 + reg) * T + tn) * FH
                                + g * 256 + u];
        if (doStore) {
#pragma unroll
            for (int reg = 0; reg < 4; ++reg)
                Hout[((size_t)(b0 + quad * 4 + reg) * T + tprev) * 512 + hofs + u]
                    = hreg[reg];
        }

        i32x4 acc[4] = {};   // per gate
#pragma unroll
        for (int kt = 0; kt < 8; ++kt) {
            u64 a = *(const u64*)&hb8[cur][r][quad * 8 + kt * 32];
#pragma unroll
            for (int g = 0; g < 4; ++g)
                acc[g] = __builtin_amdgcn_mfma_i32_16x16x32_i8(
                    (long long)a, (long long)Bq[g][kt], acc[g], 0, 0, 0);
        }

#pragma unroll
        for (int reg = 0; reg < 4; ++reg) {
            int bb = quad * 4 + reg;
            float pi = (float)acc[0][reg] * dqv[0] + bf2f(gvU[reg][0]);
            float pf = (float)acc[1][reg] * dqv[1] + bf2f(gvU[reg][1]);
            float pg = (float)acc[2][reg] * dqv[2] + bf2f(gvU[reg][2]);
            float po = (float)acc[3][reg] * dqv[3] + bf2f(gvU[reg][3]);
            float ig = sigm(pi), fg = sigm(pf), gg = tanh_(pg), og = sigm(po);
            float cn = fg * c[reg] + ig * gg;
            c[reg] = cn;
            float hn = og * tanh_(cn);
            hb8[cur ^ 1][bb][u] = (char)(int)rintf(hn * 127.0f);
            hreg[reg] = hn;
        }
        tprev = t;
        __syncthreads();   // h(s) visible; gv prefetch + Hout store retired by now
    };

    for (int s2 = 0; s2 < T; s2 += 2) {
        const int tA = rev ? (T - 1 - s2) : s2;
        const int tB = rev ? (T - 2 - s2) : (s2 + 1);
        const int tC = (s2 + 2 < T) ? (rev ? (T - 3 - s2) : (s2 + 2)) : tB;
        body(0, gvA, gvB, tA, tB, s2 > 0);   // even step: reads hb8[0], writes hb8[1]
        body(1, gvB, gvA, tB, tC, 1);        // odd step:  reads hb8[1], writes hb8[0]
    }

    // ---- epilogue: store h(T-1)
#pragma unroll
    for (int reg = 0; reg < 4; ++reg)
        Hout[((size_t)(b0 + quad * 4 + reg) * T + tprev) * 512 + hofs + u] = hreg[reg];
}

// ---------------------------------------------------------------- attention + head
__global__ __launch_bounds__(256) void attn_out_kernel(
    const float* __restrict__ senH, const float* __restrict__ tgtH,
    const float* __restrict__ Wout, const float* __restrict__ bout,
    float* __restrict__ out)
{
    int b = blockIdx.x, tid = threadIdx.x;
    __shared__ float tg[8][512];
    __shared__ float Am[128][9];
    __shared__ float rowm[128][9];
    __shared__ float mcol[8], csum[8], rvec[8], attn[128], score[512], lg[3];

    const float* tgg = tgtH + (size_t)b * 8 * 512;
    for (int i = tid; i < 4096; i += 256) tg[i >> 9][i & 511] = tgg[i];
    __syncthreads();

    {   // A[s][t] = sen_h[b,s,:] . tgt_h[b,t,:]
        int s = tid >> 1, t0 = (tid & 1) * 4;
        const float* sr = senH + ((size_t)b * 128 + s) * 512;
        float d0 = 0, d1 = 0, d2 = 0, d3 = 0;
        for (int h = 0; h < 512; ++h) {
            float x = sr[h];
            d0 += x * tg[t0 + 0][h]; d1 += x * tg[t0 + 1][h];
            d2 += x * tg[t0 + 2][h]; d3 += x * tg[t0 + 3][h];
        }
        Am[s][t0 + 0] = d0; Am[s][t0 + 1] = d1; Am[s][t0 + 2] = d2; Am[s][t0 + 3] = d3;
    }
    __syncthreads();

    if (tid < 8) {  // col-softmax stats over s, per t
        float m = -1e30f;
        for (int s = 0; s < 128; ++s) m = fmaxf(m, Am[s][tid]);
        float sum = 0;
        for (int s = 0; s < 128; ++s) sum += __expf(Am[s][tid] - m);
        mcol[tid] = m; csum[tid] = sum;
    }
    if (tid >= 64 && tid < 192) {  // row softmax per s
        int s = tid - 64;
        float m = -1e30f;
        for (int t = 0; t < 8; ++t) m = fmaxf(m, Am[s][t]);
        float e[8], sum = 0;
        for (int t = 0; t < 8; ++t) { e[t] = __expf(Am[s][t] - m); sum += e[t]; }
        float inv = __builtin_amdgcn_rcpf(sum);
        for (int t = 0; t < 8; ++t) rowm[s][t] = e[t] * inv;
    }
    __syncthreads();
    if (tid < 8) {
        float sum = 0;
        for (int s = 0; s < 128; ++s) sum += rowm[s][tid];
        rvec[tid] = sum * (1.0f / 128.0f);
    }
    __syncthreads();
    if (tid < 128) {
        float a = 0;
        for (int t = 0; t < 8; ++t)
            a += __expf(Am[tid][t] - mcol[t]) / csum[t] * rvec[t];
        attn[tid] = a;
    }
    __syncthreads();
    for (int h = tid; h < 512; h += 256) {
        float acc = 0;
        const float* sp = senH + (size_t)b * 128 * 512 + h;
        for (int s = 0; s < 128; ++s) acc += attn[s] * sp[(size_t)s * 512];
        score[h] = acc;
    }
    __syncthreads();
    if (tid < 3) {
        float acc = bout[tid];
        const float* wr = Wout + tid * 512;
        for (int h = 0; h < 512; ++h) acc += score[h] * wr[h];
        lg[tid] = acc;
    }
    __syncthreads();
    if (tid == 0) {
        float m = fmaxf(lg[0], fmaxf(lg[1], lg[2]));
        float e0 = __expf(lg[0] - m), e1 = __expf(lg[1] - m), e2 = __expf(lg[2] - m);
        float inv = 1.0f / (e0 + e1 + e2);
        out[b * 3 + 0] = e0 * inv; out[b * 3 + 1] = e1 * inv; out[b * 3 + 2] = e2 * inv;
    }
}

// ---------------------------------------------------------------- launch
extern "C" void kernel_launch(void* const* d_in, const int* in_sizes, int n_in,
                              void* d_out, int out_size, void* d_ws, size_t ws_size,
                              hipStream_t stream)
{
    const int*   sen = (const int*)d_in[0];
    const int*   tgt = (const int*)d_in[1];
    const float* emb = (const float*)d_in[2];
    Ptr4 Wih = {{(const float*)d_in[3],  (const float*)d_in[7],
                 (const float*)d_in[11], (const float*)d_in[15]}};
    Ptr4 Whh = {{(const float*)d_in[4],  (const float*)d_in[8],
                 (const float*)d_in[12], (const float*)d_in[16]}};
    Ptr4 bih = {{(const float*)d_in[5],  (const float*)d_in[9],
                 (const float*)d_in[13], (const float*)d_in[17]}};
    Ptr4 bhh = {{(const float*)d_in[6],  (const float*)d_in[10],
                 (const float*)d_in[14], (const float*)d_in[18]}};
    const float* Wout = (const float*)d_in[19];
    const float* bout = (const float*)d_in[20];
    float* out = (float*)d_out;

    char* ws = (char*)d_ws;
    size_t off = 0;
    auto alloc = [&](size_t bytes) -> void* {
        void* p = ws + off; off += (bytes + 255) & ~(size_t)255; return p;
    };
    u16*   Xs    = (u16*)alloc((size_t)16384 * KP * 2);
    u16*   Xt    = (u16*)alloc((size_t)1024 * KP * 2);
    u16*   WihB  = (u16*)alloc((size_t)4 * FH * KP * 2);
    char*  WqB   = (char*)alloc((size_t)4 * FH * HH);
    float* wdq   = (float*)alloc((size_t)4 * FH * 4);
    float* biasB = (float*)alloc((size_t)4 * FH * 4);
    u16*   Gs    = (u16*)alloc((size_t)2 * 16384 * FH * 2);
    u16*   Gt    = (u16*)alloc((size_t)2 * 1024 * FH * 2);
    float* senH  = (float*)alloc((size_t)128 * 128 * 512 * 4);
    float* tgtH  = (float*)alloc((size_t)128 * 8 * 512 * 4);
    (void)ws_size; (void)in_sizes; (void)n_in; (void)out_size;

    embed_kernel<<<17408, 128, 0, stream>>>(sen, tgt, emb, Xs, Xt);
    prep_weights_kernel<<<dim3(1280, 4), 256, 0, stream>>>(Wih, bih, bhh, WihB, biasB);
    whh_quant_kernel<<<dim3(FH, 4), 64, 0, stream>>>(Whh, WqB, wdq);

    // sen: M=16384, N=2048 (dirs 0,1). tgt: M=1024, N=2048 (dirs 2,3).
    input_gemm_kernel<<<8192, 256, 0, stream>>>(Xs, WihB, biasB, Gs,
                                                (size_t)16384 * FH);
    input_gemm_kernel<<<512, 256, 0, stream>>>(Xt, WihB + (size_t)2 * FH * KP,
                                               biasB + 2 * FH, Gt,
                                               (size_t)1024 * FH);

    lstm_scan_kernel<<<32, 1024, 0, stream>>>(WqB, wdq, Gs, Gt, senH, tgtH);
    attn_out_kernel<<<128, 256, 0, stream>>>(senH, tgtH, Wout, bout, out);
}

// Round 5
// 601.306 us; speedup vs baseline: 1.4482x; 1.4482x over previous
//
#include <hip/hip_runtime.h>

// Encoder: embed -> fused 2-dir input GEMMs (bf16 MFMA, B panel staged ONCE per block in
//          padded LDS, barrier-free K-loop; block covers 16 units x 4 GATES so the
//          gate-interleaved G store is a contiguous 8B u16x4 per lane)
//          -> 4x LSTM scan (SINGLE-WG recurrence, 1024-thr WG = 16 waves @ 4 waves/SIMD,
//             Whh as i8 row-scaled register-resident B-frags (AGPR), h double-buffered in
//             LDS, ONE barrier/step, VMEM software-pipelined one full step — R3's verified
//             310us version, gv = 4x 8B vector loads from gate-interleaved G)
//          -> co-attention + output head.
// Sizes: V=100000 E=300 H=256 OUT=3 B=128 LS=128 LT=8

typedef unsigned short u16;
typedef unsigned long long u64;
typedef float f32x4 __attribute__((ext_vector_type(4)));
typedef int   i32x4 __attribute__((ext_vector_type(4)));
typedef short bf16x8 __attribute__((ext_vector_type(8)));
typedef short s16x4 __attribute__((ext_vector_type(4)));
typedef unsigned short u16x4 __attribute__((ext_vector_type(4)));

#define KP 320   // E=300 padded to mult of 32
#define KPL 328  // LDS leading dim (u16): 656B row stride -> even bank-slot coverage, 16B aligned
#define FH 1024  // 4*H
#define HH 256   // H

struct Ptr4 { const float* p[4]; };

static __device__ __forceinline__ u16 f2bf(float f) {
    unsigned int u = __float_as_uint(f);
    u += 0x7FFFu + ((u >> 16) & 1u);          // RNE
    return (u16)(u >> 16);
}
static __device__ __forceinline__ float bf2f(u16 s) {
    return __uint_as_float((unsigned int)s << 16);
}
static __device__ __forceinline__ float sigm(float x) {
    return __builtin_amdgcn_rcpf(1.0f + __expf(-x));
}
static __device__ __forceinline__ float tanh_(float x) {
    return 1.0f - 2.0f * __builtin_amdgcn_rcpf(1.0f + __expf(2.0f * x));
}

// ---------------------------------------------------------------- embedding
__global__ void embed_kernel(const int* __restrict__ sen, const int* __restrict__ tgt,
                             const float* __restrict__ emb,
                             u16* __restrict__ Xs, u16* __restrict__ Xt)
{
    int row = blockIdx.x;
    int tok; u16* dst;
    if (row < 16384) { tok = sen[row]; dst = Xs + (size_t)row * KP; }
    else             { tok = tgt[row - 16384]; dst = Xt + (size_t)(row - 16384) * KP; }
    const float* src = emb + (size_t)tok * 300;
    for (int k = threadIdx.x; k < KP; k += blockDim.x) {
        float v = (k < 300 && tok != 0) ? src[k] : 0.0f;   // padding_idx=0
        dst[k] = f2bf(v);
    }
}

// ---------------------------------------------------------------- weight prep (all 4 dirs)
__global__ __launch_bounds__(256) void prep_weights_kernel(
    Ptr4 Wih, Ptr4 bih, Ptr4 bhh, u16* __restrict__ WihB, float* __restrict__ biasB)
{
    int dir = blockIdx.y;
    int idx = blockIdx.x * 256 + threadIdx.x;
    if (idx < FH * KP) {
        int row = idx / KP, k = idx - row * KP;
        WihB[(size_t)dir * FH * KP + idx] = (k < 300) ? f2bf(Wih.p[dir][row * 300 + k]) : (u16)0;
    }
    if (idx < FH) biasB[dir * FH + idx] = bih.p[dir][idx] + bhh.p[dir][idx];
}

// ---------------------------------------------------------------- Whh -> i8 row-scaled (all dirs)
__global__ __launch_bounds__(64) void whh_quant_kernel(
    Ptr4 Whh, char* __restrict__ Wq, float* __restrict__ wdq)
{
    int dir = blockIdx.y, row = blockIdx.x, tid = threadIdx.x;
    const float* src = Whh.p[dir] + (size_t)row * HH;
    float m = 0.0f;
    for (int k = tid; k < HH; k += 64) m = fmaxf(m, fabsf(src[k]));
    for (int off = 32; off; off >>= 1) m = fmaxf(m, __shfl_down(m, off));
    m = __shfl(m, 0);
    float qs = (m > 0.0f) ? 127.0f / m : 0.0f;
    char* dst = Wq + (size_t)dir * FH * HH + (size_t)row * HH;
    for (int k = tid; k < HH; k += 64) dst[k] = (char)(int)rintf(src[k] * qs);
    if (tid == 0) wdq[dir * FH + row] = (m > 0.0f) ? m / (127.0f * 127.0f) : 0.0f;
}

// ---------------------------------------------------------------- input GEMM (fused dir-pair)
// One launch covers TWO directions. 32 n-blocks: dirb = nblk>>4, unit tile u0=(nblk&15)*16.
// Block computes 64 m-rows x {4 gates x 16 units}: B rows staged = g*256+u0+rr, j indexes
// GATE, r indexes unit-within-tile. 64-row B panel staged ONCE in padded LDS (KPL=328:
// conflict-free b128 reads), K-loop barrier-free, A streamed from L2 (XCD swizzle keeps
// an m-tile's 32 n-blocks on one XCD). Epilogue: lane holds all 4 gates of unit u0+r =>
// ONE contiguous 8B u16x4 store to gate-interleaved G [m][unit*4+gate] (16 lanes = 128B).
// This keeps R4's coalesced stores AND R3's lstm-friendly gv layout (R4 post-mortem:
// n-major G made lstm's pregate fetch 16 scalar loads => lstm 310->573us).
__global__ __launch_bounds__(256) void input_gemm_kernel(
    const u16* __restrict__ X, const u16* __restrict__ W,
    const float* __restrict__ bias, u16* __restrict__ G, size_t dirStride)
{
    __shared__ u16 Bs[64][KPL];

    int nwg = gridDim.x;                       // multiple of 8
    int cpx = nwg >> 3;
    int wid = ((int)blockIdx.x & 7) * cpx + ((int)blockIdx.x >> 3);
    int nblk = wid & 31;                       // 32 n-blocks (2 dirs x 16 unit-tiles)
    int mblk = wid >> 5;
    int dirb = nblk >> 4;                      // 0 or 1 within the pair
    int u0   = (nblk & 15) * 16;               // unit tile base

    int tid = threadIdx.x;
    int wave = tid >> 6, lane = tid & 63;
    int r = lane & 15, quad = lane >> 4;
    int m0 = mblk * 64 + wave * 16;

    // ---- stage B panel: rows j*16+rr = W[dirb*1024 + j*256 + u0 + rr], full K=320
#pragma unroll
    for (int it = 0; it < 10; ++it) {
        int idx = it * 256 + tid;              // 64*40 chunks of 8 u16
        int row = idx / 40, cc = idx - row * 40;
        int j = row >> 4, rr = row & 15;
        bf16x8 v = *(const bf16x8*)(W + ((size_t)dirb * FH + j * 256 + u0 + rr) * KP + cc * 8);
        *(bf16x8*)&Bs[row][cc * 8] = v;
    }
    __syncthreads();

    // ---- barrier-free K loop
    const u16* xr = X + (size_t)(m0 + r) * KP + quad * 8;
    f32x4 acc[4] = {};
#pragma unroll
    for (int k0 = 0; k0 < KP; k0 += 32) {
        bf16x8 a = *(const bf16x8*)(xr + k0);
#pragma unroll
        for (int j = 0; j < 4; ++j) {
            bf16x8 b = *(const bf16x8*)&Bs[j * 16 + r][k0 + quad * 8];
            acc[j] = __builtin_amdgcn_mfma_f32_16x16x32_bf16(a, b, acc[j], 0, 0, 0);
        }
    }

    // ---- epilogue: bias + bf16; one 8B store per (reg): all 4 gates of unit u0+r
#pragma unroll
    for (int reg = 0; reg < 4; ++reg) {
        int m = m0 + quad * 4 + reg;
        int unit = u0 + r;
        u16x4 ov;
#pragma unroll
        for (int j = 0; j < 4; ++j)
            ov[j] = f2bf(acc[j][reg] + bias[dirb * FH + j * 256 + unit]);
        *(u16x4*)(G + (size_t)dirb * dirStride + (size_t)m * FH + unit * 4) = ov;
    }
}

// ---------------------------------------------------------------- LSTM scan
// R3's verified 310us version (byte-for-byte). 32 WGs x 1024 thr (16 waves; 4 waves/SIMD
// => 128-reg cap). dir = bx>>3, batch chunk = (bx&7)*16. Wave w owns units
// [w*16,w*16+16) x 4 gates = 64 Whh rows: Bq[4][8] u64 = 64 regs/lane (AGPR).
// VMEM software-pipelined one full step: gv(s+1) prefetched + h(s-1) stored at the TOP
// of step s so the vmcnt(0)-before-s_barrier drain is free. gv = 4x 8B s16x4 loads from
// gate-interleaved G [m][unit*4+gate].
// mfma_i32_16x16x32_i8: A lane(m=l&15,k=quad*8+j), B lane(n=l&15,k=quad*8+j),
// D lane(col=l&15,row=quad*4+reg) — all 4 gates of a unit land in one lane.
__global__ __launch_bounds__(1024, 1) void lstm_scan_kernel(
    const char*  __restrict__ WqB,   // [4][1024][256] i8
    const float* __restrict__ wdq,   // [4][1024] dequant scales
    const u16*   __restrict__ Gs,    // [2][16384][1024] bf16 (gate-interleaved, bias folded)
    const u16*   __restrict__ Gt,    // [2][1024][1024] bf16
    float* __restrict__ senH,        // [128][128][512]
    float* __restrict__ tgtH)        // [128][8][512]
{
    const int bx  = blockIdx.x;
    const int dir = bx >> 3;
    const int b0  = (bx & 7) << 4;
    const int T   = (dir < 2) ? 128 : 8;
    const int rev = dir & 1;

    const char* Wq = WqB + (size_t)dir * FH * HH;
    const u16*  G  = (dir < 2) ? (Gs + (size_t)dir * 16384 * FH)
                               : (Gt + (size_t)(dir - 2) * 1024 * FH);
    float* Hout = (dir < 2) ? senH : tgtH;
    const int hofs = rev ? 256 : 0;

    const int tid  = threadIdx.x;
    const int w    = tid >> 6, lane = tid & 63;
    const int r    = lane & 15, quad = lane >> 4;
    const int u    = w * 16 + r;     // this lane's unit

    __shared__ char hb8[2][16][272]; // h as i8, double-buffered (A-operand source)

    // ---- Whh i8 B-frags into registers (persist across all steps)
    // Bq[g][kt]: row = g*256 + u, k-slice = kt*32 + quad*8
    u64 Bq[4][8];
    float dqv[4];
#pragma unroll
    for (int g = 0; g < 4; ++g) {
        int row = g * 256 + u;
        dqv[g] = wdq[dir * FH + row];
#pragma unroll
        for (int kt = 0; kt < 8; ++kt)
            Bq[g][kt] = *(const u64*)(Wq + ((size_t)row << 8) + kt * 32 + quad * 8);
    }

    // ---- zero h(-1) (buffer 0; buffer 1 is written before first read)
    for (int i = tid; i < 2 * 16 * 272; i += 1024) (&hb8[0][0][0])[i] = 0;
    __syncthreads();

    float c[4] = {};      // cell state per batch-row reg
    float hreg[4] = {};   // h(s-1), stored to Hout one step late
    int tprev = 0;

    // ---- prologue: pregates for step 0
    s16x4 gvA[4], gvB[4];
    {
        const int t0 = rev ? (T - 1) : 0;
#pragma unroll
        for (int reg = 0; reg < 4; ++reg)
            gvA[reg] = *(const s16x4*)(G + ((size_t)(b0 + quad * 4 + reg) * T + t0) * FH
                                       + u * 4);
    }

    // One step: prefetch gv(next) + store h(prev) FIRST (retire under MFMA+gates),
    // then MFMA from hb8[cur], then gates -> hreg + hb8[cur^1], then barrier.
    auto body = [&](int cur, s16x4 (&gvU)[4], s16x4 (&gvP)[4],
                    int t, int tn, int doStore) {
#pragma unroll
        for (int reg = 0; reg < 4; ++reg)
            gvP[reg] = *(const s16x4*)(G + ((size_t)(b0 + quad * 4 + reg) * T + tn) * FH
                                       + u * 4);
        if (doStore) {
#pragma unroll
            for (int reg = 0; reg < 4; ++reg)
                Hout[((size_t)(b0 + quad * 4 + reg) * T + tprev) * 512 + hofs + u]
                    = hreg[reg];
        }

        i32x4 acc[4] = {};   // per gate
#pragma unroll
        for (int kt = 0; kt < 8; ++kt) {
            u64 a = *(const u64*)&hb8[cur][r][quad * 8 + kt * 32];
#pragma unroll
            for (int g = 0; g < 4; ++g)
                acc[g] = __builtin_amdgcn_mfma_i32_16x16x32_i8(
                    (long long)a, (long long)Bq[g][kt], acc[g], 0, 0, 0);
        }

#pragma unroll
        for (int reg = 0; reg < 4; ++reg) {
            int bb = quad * 4 + reg;
            float pi = (float)acc[0][reg] * dqv[0] + bf2f((u16)gvU[reg].x);
            float pf = (float)acc[1][reg] * dqv[1] + bf2f((u16)gvU[reg].y);
            float pg = (float)acc[2][reg] * dqv[2] + bf2f((u16)gvU[reg].z);
            float po = (float)acc[3][reg] * dqv[3] + bf2f((u16)gvU[reg].w);
            float ig = sigm(pi), fg = sigm(pf), gg = tanh_(pg), og = sigm(po);
            float cn = fg * c[reg] + ig * gg;
            c[reg] = cn;
            float hn = og * tanh_(cn);
            hb8[cur ^ 1][bb][u] = (char)(int)rintf(hn * 127.0f);
            hreg[reg] = hn;
        }
        tprev = t;
        __syncthreads();   // h(s) visible; gv prefetch + Hout store retired by now
    };

    for (int s2 = 0; s2 < T; s2 += 2) {
        const int tA = rev ? (T - 1 - s2) : s2;
        const int tB = rev ? (T - 2 - s2) : (s2 + 1);
        const int tC = (s2 + 2 < T) ? (rev ? (T - 3 - s2) : (s2 + 2)) : tB;
        body(0, gvA, gvB, tA, tB, s2 > 0);   // even step: reads hb8[0], writes hb8[1]
        body(1, gvB, gvA, tB, tC, 1);        // odd step:  reads hb8[1], writes hb8[0]
    }

    // ---- epilogue: store h(T-1)
#pragma unroll
    for (int reg = 0; reg < 4; ++reg)
        Hout[((size_t)(b0 + quad * 4 + reg) * T + tprev) * 512 + hofs + u] = hreg[reg];
}

// ---------------------------------------------------------------- attention + head
__global__ __launch_bounds__(256) void attn_out_kernel(
    const float* __restrict__ senH, const float* __restrict__ tgtH,
    const float* __restrict__ Wout, const float* __restrict__ bout,
    float* __restrict__ out)
{
    int b = blockIdx.x, tid = threadIdx.x;
    __shared__ float tg[8][512];
    __shared__ float Am[128][9];
    __shared__ float rowm[128][9];
    __shared__ float mcol[8], csum[8], rvec[8], attn[128], score[512], lg[3];

    const float* tgg = tgtH + (size_t)b * 8 * 512;
    for (int i = tid; i < 4096; i += 256) tg[i >> 9][i & 511] = tgg[i];
    __syncthreads();

    {   // A[s][t] = sen_h[b,s,:] . tgt_h[b,t,:]
        int s = tid >> 1, t0 = (tid & 1) * 4;
        const float* sr = senH + ((size_t)b * 128 + s) * 512;
        float d0 = 0, d1 = 0, d2 = 0, d3 = 0;
        for (int h = 0; h < 512; ++h) {
            float x = sr[h];
            d0 += x * tg[t0 + 0][h]; d1 += x * tg[t0 + 1][h];
            d2 += x * tg[t0 + 2][h]; d3 += x * tg[t0 + 3][h];
        }
        Am[s][t0 + 0] = d0; Am[s][t0 + 1] = d1; Am[s][t0 + 2] = d2; Am[s][t0 + 3] = d3;
    }
    __syncthreads();

    if (tid < 8) {  // col-softmax stats over s, per t
        float m = -1e30f;
        for (int s = 0; s < 128; ++s) m = fmaxf(m, Am[s][tid]);
        float sum = 0;
        for (int s = 0; s < 128; ++s) sum += __expf(Am[s][tid] - m);
        mcol[tid] = m; csum[tid] = sum;
    }
    if (tid >= 64 && tid < 192) {  // row softmax per s
        int s = tid - 64;
        float m = -1e30f;
        for (int t = 0; t < 8; ++t) m = fmaxf(m, Am[s][t]);
        float e[8], sum = 0;
        for (int t = 0; t < 8; ++t) { e[t] = __expf(Am[s][t] - m); sum += e[t]; }
        float inv = __builtin_amdgcn_rcpf(sum);
        for (int t = 0; t < 8; ++t) rowm[s][t] = e[t] * inv;
    }
    __syncthreads();
    if (tid < 8) {
        float sum = 0;
        for (int s = 0; s < 128; ++s) sum += rowm[s][tid];
        rvec[tid] = sum * (1.0f / 128.0f);
    }
    __syncthreads();
    if (tid < 128) {
        float a = 0;
        for (int t = 0; t < 8; ++t)
            a += __expf(Am[tid][t] - mcol[t]) / csum[t] * rvec[t];
        attn[tid] = a;
    }
    __syncthreads();
    for (int h = tid; h < 512; h += 256) {
        float acc = 0;
        const float* sp = senH + (size_t)b * 128 * 512 + h;
        for (int s = 0; s < 128; ++s) acc += attn[s] * sp[(size_t)s * 512];
        score[h] = acc;
    }
    __syncthreads();
    if (tid < 3) {
        float acc = bout[tid];
        const float* wr = Wout + tid * 512;
        for (int h = 0; h < 512; ++h) acc += score[h] * wr[h];
        lg[tid] = acc;
    }
    __syncthreads();
    if (tid == 0) {
        float m = fmaxf(lg[0], fmaxf(lg[1], lg[2]));
        float e0 = __expf(lg[0] - m), e1 = __expf(lg[1] - m), e2 = __expf(lg[2] - m);
        float inv = 1.0f / (e0 + e1 + e2);
        out[b * 3 + 0] = e0 * inv; out[b * 3 + 1] = e1 * inv; out[b * 3 + 2] = e2 * inv;
    }
}

// ---------------------------------------------------------------- launch
extern "C" void kernel_launch(void* const* d_in, const int* in_sizes, int n_in,
                              void* d_out, int out_size, void* d_ws, size_t ws_size,
                              hipStream_t stream)
{
    const int*   sen = (const int*)d_in[0];
    const int*   tgt = (const int*)d_in[1];
    const float* emb = (const float*)d_in[2];
    Ptr4 Wih = {{(const float*)d_in[3],  (const float*)d_in[7],
                 (const float*)d_in[11], (const float*)d_in[15]}};
    Ptr4 Whh = {{(const float*)d_in[4],  (const float*)d_in[8],
                 (const float*)d_in[12], (const float*)d_in[16]}};
    Ptr4 bih = {{(const float*)d_in[5],  (const float*)d_in[9],
                 (const float*)d_in[13], (const float*)d_in[17]}};
    Ptr4 bhh = {{(const float*)d_in[6],  (const float*)d_in[10],
                 (const float*)d_in[14], (const float*)d_in[18]}};
    const float* Wout = (const float*)d_in[19];
    const float* bout = (const float*)d_in[20];
    float* out = (float*)d_out;

    char* ws = (char*)d_ws;
    size_t off = 0;
    auto alloc = [&](size_t bytes) -> void* {
        void* p = ws + off; off += (bytes + 255) & ~(size_t)255; return p;
    };
    u16*   Xs    = (u16*)alloc((size_t)16384 * KP * 2);
    u16*   Xt    = (u16*)alloc((size_t)1024 * KP * 2);
    u16*   WihB  = (u16*)alloc((size_t)4 * FH * KP * 2);
    char*  WqB   = (char*)alloc((size_t)4 * FH * HH);
    float* wdq   = (float*)alloc((size_t)4 * FH * 4);
    float* biasB = (float*)alloc((size_t)4 * FH * 4);
    u16*   Gs    = (u16*)alloc((size_t)2 * 16384 * FH * 2);
    u16*   Gt    = (u16*)alloc((size_t)2 * 1024 * FH * 2);
    float* senH  = (float*)alloc((size_t)128 * 128 * 512 * 4);
    float* tgtH  = (float*)alloc((size_t)128 * 8 * 512 * 4);
    (void)ws_size; (void)in_sizes; (void)n_in; (void)out_size;

    embed_kernel<<<17408, 128, 0, stream>>>(sen, tgt, emb, Xs, Xt);
    prep_weights_kernel<<<dim3(1280, 4), 256, 0, stream>>>(Wih, bih, bhh, WihB, biasB);
    whh_quant_kernel<<<dim3(FH, 4), 64, 0, stream>>>(Whh, WqB, wdq);

    // sen: M=16384 (dirs 0,1). tgt: M=1024 (dirs 2,3). 32 n-blocks each.
    input_gemm_kernel<<<8192, 256, 0, stream>>>(Xs, WihB, biasB, Gs,
                                                (size_t)16384 * FH);
    input_gemm_kernel<<<512, 256, 0, stream>>>(Xt, WihB + (size_t)2 * FH * KP,
                                               biasB + 2 * FH, Gt,
                                               (size_t)1024 * FH);

    lstm_scan_kernel<<<32, 1024, 0, stream>>>(WqB, wdq, Gs, Gt, senH, tgtH);
    attn_out_kernel<<<128, 256, 0, stream>>>(senH, tgtH, Wout, bout, out);
}

// Round 6
// 577.359 us; speedup vs baseline: 1.5082x; 1.0415x over previous
//
#include <hip/hip_runtime.h>

// Encoder: fused pre (embed + weight-prep + Whh-quant, one launch)
//          -> fused input GEMM (sen+tgt one launch; bf16 MFMA, B panel staged once in
//             padded LDS, barrier-free K-loop; 16-unit x 4-gate tiles => contiguous 8B
//             gate-interleaved stores into TIME-MAJOR G [t][b][4H])
//          -> 4x LSTM scan (SINGLE-WG recurrence, 1024-thr WG, 4 waves/SIMD;
//             Whh as i8 B-frags in AGPR, mfma_i32_16x16x64_i8 (16/step, halved issue),
//             exp2-prescaled gates, h dbuf LDS, ONE barrier/step, VMEM pipelined 1 step)
//          -> co-attention + output head.
// Sizes: V=100000 E=300 H=256 OUT=3 B=128 LS=128 LT=8

typedef unsigned short u16;
typedef unsigned long long u64;
typedef float f32x4 __attribute__((ext_vector_type(4)));
typedef int   i32x4 __attribute__((ext_vector_type(4)));
typedef short bf16x8 __attribute__((ext_vector_type(8)));
typedef short s16x4 __attribute__((ext_vector_type(4)));
typedef unsigned short u16x4 __attribute__((ext_vector_type(4)));

#define KP 320   // E=300 padded to mult of 32
#define KPL 328  // LDS leading dim (u16): 656B row stride, 16B aligned, conflict-benign
#define FH 1024  // 4*H
#define HH 256   // H
#define L2E 1.4426950408889634f

struct Ptr4 { const float* p[4]; };

static __device__ __forceinline__ u16 f2bf(float f) {
    unsigned int u = __float_as_uint(f);
    u += 0x7FFFu + ((u >> 16) & 1u);          // RNE
    return (u16)(u >> 16);
}
static __device__ __forceinline__ float bf2f(u16 s) {
    return __uint_as_float((unsigned int)s << 16);
}
// pre-scaled activations: input already multiplied by log2e (sigm) / 2*log2e (tanh2)
static __device__ __forceinline__ float sigm2(float x) {   // sigmoid(raw), x = raw*log2e
    return __builtin_amdgcn_rcpf(1.0f + __builtin_amdgcn_exp2f(-x));
}
static __device__ __forceinline__ float tanh2(float x) {   // tanh(raw), x = raw*2*log2e
    return 1.0f - 2.0f * __builtin_amdgcn_rcpf(1.0f + __builtin_amdgcn_exp2f(x));
}
static __device__ __forceinline__ float tanh_(float x) {   // natural input (cell state)
    return 1.0f - 2.0f * __builtin_amdgcn_rcpf(1.0f + __expf(2.0f * x));
}

// ---------------------------------------------------------------- fused pre
// blocks [0,17408): embed   [17408,22528): Wih/bias prep   [22528,23552): Whh quant.
// Prep folds the activation prescale (log2e; 2*log2e for gate 2) into WihB, biasB, wdq
// so the lstm's exp calls need no multiply (v_exp_f32 computes 2^x natively).
__global__ __launch_bounds__(256) void pre_kernel(
    const int* __restrict__ sen, const int* __restrict__ tgt,
    const float* __restrict__ emb, Ptr4 Wih, Ptr4 Whh, Ptr4 bih, Ptr4 bhh,
    u16* __restrict__ Xs, u16* __restrict__ Xt,
    u16* __restrict__ WihB, float* __restrict__ biasB,
    char* __restrict__ Wq, float* __restrict__ wdq)
{
    int bid = blockIdx.x, tid = threadIdx.x;
    if (bid < 17408) {                       // ---- embedding
        int row = bid;
        int tok; u16* dst;
        if (row < 16384) { tok = sen[row]; dst = Xs + (size_t)row * KP; }
        else             { tok = tgt[row - 16384]; dst = Xt + (size_t)(row - 16384) * KP; }
        const float* src = emb + (size_t)tok * 300;
        for (int k = tid; k < KP; k += 256) {
            float v = (k < 300 && tok != 0) ? src[k] : 0.0f;   // padding_idx=0
            dst[k] = f2bf(v);
        }
    } else if (bid < 22528) {                // ---- Wih -> bf16 (prescaled), bias fold
        int local = bid - 17408;
        int dir = local / 1280, blk = local - dir * 1280;
        int idx = blk * 256 + tid;
        if (idx < FH * KP) {
            int row = idx / KP, k = idx - row * KP;
            float gsc = ((row >> 8) == 2) ? 2.0f * L2E : L2E;
            WihB[(size_t)dir * FH * KP + idx] =
                (k < 300) ? f2bf(Wih.p[dir][row * 300 + k] * gsc) : (u16)0;
        }
        if (idx < FH) {
            float gsc = ((idx >> 8) == 2) ? 2.0f * L2E : L2E;
            biasB[dir * FH + idx] = (bih.p[dir][idx] + bhh.p[dir][idx]) * gsc;
        }
    } else {                                 // ---- Whh -> i8 row-scaled (prescaled wdq)
        int local = bid - 22528;
        int w = tid >> 6, lane = tid & 63;
        int pair = local * 4 + w;
        int dir = pair >> 10, row = pair & 1023;
        const float* src = Whh.p[dir] + (size_t)row * HH;
        float m = 0.0f;
        for (int k = lane; k < HH; k += 64) m = fmaxf(m, fabsf(src[k]));
        for (int off = 32; off; off >>= 1) m = fmaxf(m, __shfl_down(m, off));
        m = __shfl(m, 0);
        float qs = (m > 0.0f) ? 127.0f / m : 0.0f;
        char* dst = Wq + (size_t)dir * FH * HH + (size_t)row * HH;
        for (int k = lane; k < HH; k += 64) dst[k] = (char)(int)rintf(src[k] * qs);
        if (lane == 0) {
            float gsc = ((row >> 8) == 2) ? 2.0f * L2E : L2E;
            wdq[dir * FH + row] = (m > 0.0f) ? m / (127.0f * 127.0f) * gsc : 0.0f;
        }
    }
}

// ---------------------------------------------------------------- fused input GEMM
// bid<8192: sen (M=16384, dirs 0,1, T=128).  bid>=8192: tgt (M=1024, dirs 2,3, T=8).
// 32 n-blocks per pair: dirb=nblk>>4, unit tile u0=(nblk&15)*16; B rows g*256+u0+rr.
// B panel staged ONCE in padded LDS, barrier-free K-loop, XCD swizzle for L2 locality.
// Epilogue: lane holds all 4 gates of unit u0+r => one contiguous 8B u16x4 store into
// TIME-MAJOR G [t][b][unit*4+gate] (b=m>>tsh, t=m&(T-1); 16 lanes = 128B segments).
__global__ __launch_bounds__(256) void input_gemm_kernel(
    const u16* __restrict__ Xs, const u16* __restrict__ Xt,
    const u16* __restrict__ WihB, const float* __restrict__ biasB,
    u16* __restrict__ Gs, u16* __restrict__ Gt)
{
    __shared__ u16 Bs[64][KPL];

    int bid = blockIdx.x;
    const u16* X; const u16* W; const float* bias; u16* G;
    int lbid, nwg, tsh;
    if (bid < 8192) { lbid = bid;        nwg = 8192; tsh = 7;
                      X = Xs; W = WihB;                         bias = biasB;          G = Gs; }
    else            { lbid = bid - 8192; nwg = 512;  tsh = 3;
                      X = Xt; W = WihB + (size_t)2 * FH * KP;   bias = biasB + 2 * FH; G = Gt; }

    int cpx = nwg >> 3;
    int wid = (lbid & 7) * cpx + (lbid >> 3);
    int nblk = wid & 31;
    int mblk = wid >> 5;
    int dirb = nblk >> 4;
    int u0   = (nblk & 15) * 16;
    size_t dirStride = (size_t)(tsh == 7 ? 16384 : 1024) * FH;

    int tid = threadIdx.x;
    int wave = tid >> 6, lane = tid & 63;
    int r = lane & 15, quad = lane >> 4;
    int m0 = mblk * 64 + wave * 16;

    // ---- stage B panel: rows j*16+rr = W[dirb*1024 + j*256 + u0 + rr], full K=320
#pragma unroll
    for (int it = 0; it < 10; ++it) {
        int idx = it * 256 + tid;
        int row = idx / 40, cc = idx - row * 40;
        int j = row >> 4, rr = row & 15;
        bf16x8 v = *(const bf16x8*)(W + ((size_t)dirb * FH + j * 256 + u0 + rr) * KP + cc * 8);
        *(bf16x8*)&Bs[row][cc * 8] = v;
    }
    __syncthreads();

    // ---- barrier-free K loop
    const u16* xr = X + (size_t)(m0 + r) * KP + quad * 8;
    f32x4 acc[4] = {};
#pragma unroll
    for (int k0 = 0; k0 < KP; k0 += 32) {
        bf16x8 a = *(const bf16x8*)(xr + k0);
#pragma unroll
        for (int j = 0; j < 4; ++j) {
            bf16x8 b = *(const bf16x8*)&Bs[j * 16 + r][k0 + quad * 8];
            acc[j] = __builtin_amdgcn_mfma_f32_16x16x32_bf16(a, b, acc[j], 0, 0, 0);
        }
    }

    // ---- epilogue: bias + bf16; one 8B store per reg into time-major G
#pragma unroll
    for (int reg = 0; reg < 4; ++reg) {
        int m = m0 + quad * 4 + reg;
        int b = m >> tsh, t = m & ((1 << tsh) - 1);
        int unit = u0 + r;
        u16x4 ov;
#pragma unroll
        for (int j = 0; j < 4; ++j)
            ov[j] = f2bf(acc[j][reg] + bias[dirb * FH + j * 256 + unit]);
        *(u16x4*)(G + (size_t)dirb * dirStride + ((size_t)t * 128 + b) * FH + unit * 4) = ov;
    }
}

// ---------------------------------------------------------------- LSTM scan
// 32 WGs x 1024 thr (16 waves; 4 waves/SIMD => 128-reg unified cap). dir = bx>>3,
// batch chunk = (bx&7)*16. Wave w owns units [w*16,w*16+16) x 4 gates = 64 Whh rows.
// Bq[4][4] i32x4 = 64 regs/lane of i8 B-frags (AGPR). Recurrent matmul uses
// mfma_i32_16x16x64_i8: 16 MFMAs + 4 ds_read_b128 per step (R5 ran 32 + 8 with K=32 —
// the active-CU pipes were ~74% busy, so issue count is the lever). Gates use
// exp2-prescaled inputs (prescale folded into G/wdq at prep). G is TIME-MAJOR
// [t][b][4H]: per-step gv loads hit one contiguous 32KB/WG slab.
// VMEM software-pipelined one full step: gv(s+1) prefetched + h(s-1) stored at the TOP
// of step s so the vmcnt(0)-before-s_barrier drain is free (R3 verified).
// mfma 16x16xK frag pattern: A lane(m=l&15, k=quad*16+j), B lane(n=l&15, k=quad*16+j),
// D lane(col=l&15, row=quad*4+reg) — all 4 gates of a unit land in one lane.
__global__ __launch_bounds__(1024, 1) void lstm_scan_kernel(
    const char*  __restrict__ WqB,   // [4][1024][256] i8
    const float* __restrict__ wdq,   // [4][1024] dequant scales (prescaled)
    const u16*   __restrict__ Gs,    // [2][128t][128b][1024] bf16
    const u16*   __restrict__ Gt,    // [2][8t][128b][1024] bf16
    float* __restrict__ senH,        // [128][128][512]
    float* __restrict__ tgtH)        // [128][8][512]
{
    const int bx  = blockIdx.x;
    const int dir = bx >> 3;
    const int b0  = (bx & 7) << 4;
    const int T   = (dir < 2) ? 128 : 8;
    const int rev = dir & 1;

    const char* Wq = WqB + (size_t)dir * FH * HH;
    const u16*  G  = (dir < 2) ? (Gs + (size_t)dir * 16384 * FH)
                               : (Gt + (size_t)(dir - 2) * 1024 * FH);
    float* Hout = (dir < 2) ? senH : tgtH;
    const int hofs = rev ? 256 : 0;

    const int tid  = threadIdx.x;
    const int w    = tid >> 6, lane = tid & 63;
    const int r    = lane & 15, quad = lane >> 4;
    const int u    = w * 16 + r;     // this lane's unit

    __shared__ __align__(16) char hb8[2][16][272]; // h as i8, double-buffered

    // ---- Whh i8 B-frags into registers (persist across all steps)
    // Bq[g][kt]: row = g*256 + u, k-slice = kt*64 + quad*16 (16B)
    i32x4 Bq[4][4];
    float dqv[4];
#pragma unroll
    for (int g = 0; g < 4; ++g) {
        int row = g * 256 + u;
        dqv[g] = wdq[dir * FH + row];
#pragma unroll
        for (int kt = 0; kt < 4; ++kt)
            Bq[g][kt] = *(const i32x4*)(Wq + ((size_t)row << 8) + kt * 64 + quad * 16);
    }

    // ---- zero h(-1)
    for (int i = tid; i < 2 * 16 * 272; i += 1024) (&hb8[0][0][0])[i] = 0;
    __syncthreads();

    float c[4] = {};      // cell state per batch-row reg
    float hreg[4] = {};   // h(s-1), stored to Hout one step late
    int tprev = 0;

    // ---- prologue: pregates for step 0
    s16x4 gvA[4], gvB[4];
    {
        const int t0 = rev ? (T - 1) : 0;
#pragma unroll
        for (int reg = 0; reg < 4; ++reg)
            gvA[reg] = *(const s16x4*)(G + ((size_t)t0 * 128 + b0 + quad * 4 + reg) * FH
                                       + u * 4);
    }

    // One step: prefetch gv(next) + store h(prev) FIRST (retire under MFMA+gates),
    // then MFMA from hb8[cur], then gates -> hreg + hb8[cur^1], then barrier.
    auto body = [&](int cur, s16x4 (&gvU)[4], s16x4 (&gvP)[4],
                    int t, int tn, int doStore) {
#pragma unroll
        for (int reg = 0; reg < 4; ++reg)
            gvP[reg] = *(const s16x4*)(G + ((size_t)tn * 128 + b0 + quad * 4 + reg) * FH
                                       + u * 4);
        if (doStore) {
#pragma unroll
            for (int reg = 0; reg < 4; ++reg)
                Hout[((size_t)(b0 + quad * 4 + reg) * T + tprev) * 512 + hofs + u]
                    = hreg[reg];
        }

        i32x4 acc[4] = {};   // per gate
#pragma unroll
        for (int kt = 0; kt < 4; ++kt) {
            i32x4 a = *(const i32x4*)&hb8[cur][r][kt * 64 + quad * 16];
#pragma unroll
            for (int g = 0; g < 4; ++g)
                acc[g] = __builtin_amdgcn_mfma_i32_16x16x64_i8(a, Bq[g][kt], acc[g], 0, 0, 0);
        }

#pragma unroll
        for (int reg = 0; reg < 4; ++reg) {
            int bb = quad * 4 + reg;
            float pi = (float)acc[0][reg] * dqv[0] + bf2f((u16)gvU[reg].x);
            float pf = (float)acc[1][reg] * dqv[1] + bf2f((u16)gvU[reg].y);
            float pg = (float)acc[2][reg] * dqv[2] + bf2f((u16)gvU[reg].z);
            float po = (float)acc[3][reg] * dqv[3] + bf2f((u16)gvU[reg].w);
            float ig = sigm2(pi), fg = sigm2(pf), gg = tanh2(pg), og = sigm2(po);
            float cn = fg * c[reg] + ig * gg;
            c[reg] = cn;
            float hn = og * tanh_(cn);
            hb8[cur ^ 1][bb][u] = (char)(int)rintf(hn * 127.0f);
            hreg[reg] = hn;
        }
        tprev = t;
        __syncthreads();   // h(s) visible; gv prefetch + Hout store retired by now
    };

    for (int s2 = 0; s2 < T; s2 += 2) {
        const int tA = rev ? (T - 1 - s2) : s2;
        const int tB = rev ? (T - 2 - s2) : (s2 + 1);
        const int tC = (s2 + 2 < T) ? (rev ? (T - 3 - s2) : (s2 + 2)) : tB;
        body(0, gvA, gvB, tA, tB, s2 > 0);   // even step: reads hb8[0], writes hb8[1]
        body(1, gvB, gvA, tB, tC, 1);        // odd step:  reads hb8[1], writes hb8[0]
    }

    // ---- epilogue: store h(T-1)
#pragma unroll
    for (int reg = 0; reg < 4; ++reg)
        Hout[((size_t)(b0 + quad * 4 + reg) * T + tprev) * 512 + hofs + u] = hreg[reg];
}

// ---------------------------------------------------------------- attention + head
__global__ __launch_bounds__(256) void attn_out_kernel(
    const float* __restrict__ senH, const float* __restrict__ tgtH,
    const float* __restrict__ Wout, const float* __restrict__ bout,
    float* __restrict__ out)
{
    int b = blockIdx.x, tid = threadIdx.x;
    __shared__ float tg[8][512];
    __shared__ float Am[128][9];
    __shared__ float rowm[128][9];
    __shared__ float mcol[8], csum[8], rvec[8], attn[128], score[512], lg[3];

    const float* tgg = tgtH + (size_t)b * 8 * 512;
    for (int i = tid; i < 4096; i += 256) tg[i >> 9][i & 511] = tgg[i];
    __syncthreads();

    {   // A[s][t] = sen_h[b,s,:] . tgt_h[b,t,:]
        int s = tid >> 1, t0 = (tid & 1) * 4;
        const float* sr = senH + ((size_t)b * 128 + s) * 512;
        float d0 = 0, d1 = 0, d2 = 0, d3 = 0;
        for (int h = 0; h < 512; ++h) {
            float x = sr[h];
            d0 += x * tg[t0 + 0][h]; d1 += x * tg[t0 + 1][h];
            d2 += x * tg[t0 + 2][h]; d3 += x * tg[t0 + 3][h];
        }
        Am[s][t0 + 0] = d0; Am[s][t0 + 1] = d1; Am[s][t0 + 2] = d2; Am[s][t0 + 3] = d3;
    }
    __syncthreads();

    if (tid < 8) {  // col-softmax stats over s, per t
        float m = -1e30f;
        for (int s = 0; s < 128; ++s) m = fmaxf(m, Am[s][tid]);
        float sum = 0;
        for (int s = 0; s < 128; ++s) sum += __expf(Am[s][tid] - m);
        mcol[tid] = m; csum[tid] = sum;
    }
    if (tid >= 64 && tid < 192) {  // row softmax per s
        int s = tid - 64;
        float m = -1e30f;
        for (int t = 0; t < 8; ++t) m = fmaxf(m, Am[s][t]);
        float e[8], sum = 0;
        for (int t = 0; t < 8; ++t) { e[t] = __expf(Am[s][t] - m); sum += e[t]; }
        float inv = __builtin_amdgcn_rcpf(sum);
        for (int t = 0; t < 8; ++t) rowm[s][t] = e[t] * inv;
    }
    __syncthreads();
    if (tid < 8) {
        float sum = 0;
        for (int s = 0; s < 128; ++s) sum += rowm[s][tid];
        rvec[tid] = sum * (1.0f / 128.0f);
    }
    __syncthreads();
    if (tid < 128) {
        float a = 0;
        for (int t = 0; t < 8; ++t)
            a += __expf(Am[tid][t] - mcol[t]) / csum[t] * rvec[t];
        attn[tid] = a;
    }
    __syncthreads();
    for (int h = tid; h < 512; h += 256) {
        float acc = 0;
        const float* sp = senH + (size_t)b * 128 * 512 + h;
        for (int s = 0; s < 128; ++s) acc += attn[s] * sp[(size_t)s * 512];
        score[h] = acc;
    }
    __syncthreads();
    if (tid < 3) {
        float acc = bout[tid];
        const float* wr = Wout + tid * 512;
        for (int h = 0; h < 512; ++h) acc += score[h] * wr[h];
        lg[tid] = acc;
    }
    __syncthreads();
    if (tid == 0) {
        float m = fmaxf(lg[0], fmaxf(lg[1], lg[2]));
        float e0 = __expf(lg[0] - m), e1 = __expf(lg[1] - m), e2 = __expf(lg[2] - m);
        float inv = 1.0f / (e0 + e1 + e2);
        out[b * 3 + 0] = e0 * inv; out[b * 3 + 1] = e1 * inv; out[b * 3 + 2] = e2 * inv;
    }
}

// ---------------------------------------------------------------- launch
extern "C" void kernel_launch(void* const* d_in, const int* in_sizes, int n_in,
                              void* d_out, int out_size, void* d_ws, size_t ws_size,
                              hipStream_t stream)
{
    const int*   sen = (const int*)d_in[0];
    const int*   tgt = (const int*)d_in[1];
    const float* emb = (const float*)d_in[2];
    Ptr4 Wih = {{(const float*)d_in[3],  (const float*)d_in[7],
                 (const float*)d_in[11], (const float*)d_in[15]}};
    Ptr4 Whh = {{(const float*)d_in[4],  (const float*)d_in[8],
                 (const float*)d_in[12], (const float*)d_in[16]}};
    Ptr4 bih = {{(const float*)d_in[5],  (const float*)d_in[9],
                 (const float*)d_in[13], (const float*)d_in[17]}};
    Ptr4 bhh = {{(const float*)d_in[6],  (const float*)d_in[10],
                 (const float*)d_in[14], (const float*)d_in[18]}};
    const float* Wout = (const float*)d_in[19];
    const float* bout = (const float*)d_in[20];
    float* out = (float*)d_out;

    char* ws = (char*)d_ws;
    size_t off = 0;
    auto alloc = [&](size_t bytes) -> void* {
        void* p = ws + off; off += (bytes + 255) & ~(size_t)255; return p;
    };
    u16*   Xs    = (u16*)alloc((size_t)16384 * KP * 2);
    u16*   Xt    = (u16*)alloc((size_t)1024 * KP * 2);
    u16*   WihB  = (u16*)alloc((size_t)4 * FH * KP * 2);
    char*  WqB   = (char*)alloc((size_t)4 * FH * HH);
    float* wdq   = (float*)alloc((size_t)4 * FH * 4);
    float* biasB = (float*)alloc((size_t)4 * FH * 4);
    u16*   Gs    = (u16*)alloc((size_t)2 * 16384 * FH * 2);
    u16*   Gt    = (u16*)alloc((size_t)2 * 1024 * FH * 2);
    float* senH  = (float*)alloc((size_t)128 * 128 * 512 * 4);
    float* tgtH  = (float*)alloc((size_t)128 * 8 * 512 * 4);
    (void)ws_size; (void)in_sizes; (void)n_in; (void)out_size;

    pre_kernel<<<23552, 256, 0, stream>>>(sen, tgt, emb, Wih, Whh, bih, bhh,
                                          Xs, Xt, WihB, biasB, WqB, wdq);
    input_gemm_kernel<<<8704, 256, 0, stream>>>(Xs, Xt, WihB, biasB, Gs, Gt);
    lstm_scan_kernel<<<32, 1024, 0, stream>>>(WqB, wdq, Gs, Gt, senH, tgtH);
    attn_out_kernel<<<128, 256, 0, stream>>>(senH, tgtH, Wout, bout, out);
}

// Round 7
// 503.895 us; speedup vs baseline: 1.7281x; 1.1458x over previous
//
#include <hip/hip_runtime.h>

// Encoder: fused pre (embed + weight-prep + Whh-quant, one launch)
//          -> fused input GEMM (sen+tgt one launch; bf16 MFMA, 128-row m-tiles, B panel
//             staged once in padded LDS, barrier-free K-loop; 16-unit x 4-gate tiles =>
//             contiguous 8B gate-interleaved stores into TIME-MAJOR G [t][b][4H])
//          -> 4x LSTM scan (SINGLE-WG recurrence, 1024-thr WG, 4 waves/SIMD;
//             Whh i8 B-frags in AGPR, mfma_i32_16x16x64_i8, exp2-prescaled gates,
//             h dbuf LDS, ONE barrier/step, VMEM pipelined 1 step, and POINTER-MARCHED
//             g/h addresses: time-major G AND time-major H give uniform per-step strides)
//          -> co-attention + output head (reads time-major H).
// Sizes: V=100000 E=300 H=256 OUT=3 B=128 LS=128 LT=8

typedef unsigned short u16;
typedef unsigned long long u64;
typedef float f32x4 __attribute__((ext_vector_type(4)));
typedef int   i32x4 __attribute__((ext_vector_type(4)));
typedef short bf16x8 __attribute__((ext_vector_type(8)));
typedef short s16x4 __attribute__((ext_vector_type(4)));
typedef unsigned short u16x4 __attribute__((ext_vector_type(4)));

#define KP 320   // E=300 padded to mult of 32
#define KPL 328  // LDS leading dim (u16): 656B row stride, 16B aligned
#define FH 1024  // 4*H
#define HH 256   // H
#define L2E 1.4426950408889634f

struct Ptr4 { const float* p[4]; };

static __device__ __forceinline__ u16 f2bf(float f) {
    unsigned int u = __float_as_uint(f);
    u += 0x7FFFu + ((u >> 16) & 1u);          // RNE
    return (u16)(u >> 16);
}
static __device__ __forceinline__ float bf2f(u16 s) {
    return __uint_as_float((unsigned int)s << 16);
}
// pre-scaled activations: input already multiplied by log2e (sigm2) / 2*log2e (tanh2)
static __device__ __forceinline__ float sigm2(float x) {   // sigmoid(raw), x = raw*log2e
    return __builtin_amdgcn_rcpf(1.0f + __builtin_amdgcn_exp2f(-x));
}
static __device__ __forceinline__ float tanh2(float x) {   // tanh(raw), x = raw*2*log2e
    return 1.0f - 2.0f * __builtin_amdgcn_rcpf(1.0f + __builtin_amdgcn_exp2f(x));
}

// ---------------------------------------------------------------- fused pre
// blocks [0,17408): embed   [17408,22528): Wih/bias prep   [22528,23552): Whh quant.
__global__ __launch_bounds__(256) void pre_kernel(
    const int* __restrict__ sen, const int* __restrict__ tgt,
    const float* __restrict__ emb, Ptr4 Wih, Ptr4 Whh, Ptr4 bih, Ptr4 bhh,
    u16* __restrict__ Xs, u16* __restrict__ Xt,
    u16* __restrict__ WihB, float* __restrict__ biasB,
    char* __restrict__ Wq, float* __restrict__ wdq)
{
    int bid = blockIdx.x, tid = threadIdx.x;
    if (bid < 17408) {                       // ---- embedding
        int row = bid;
        int tok; u16* dst;
        if (row < 16384) { tok = sen[row]; dst = Xs + (size_t)row * KP; }
        else             { tok = tgt[row - 16384]; dst = Xt + (size_t)(row - 16384) * KP; }
        const float* src = emb + (size_t)tok * 300;
        for (int k = tid; k < KP; k += 256) {
            float v = (k < 300 && tok != 0) ? src[k] : 0.0f;   // padding_idx=0
            dst[k] = f2bf(v);
        }
    } else if (bid < 22528) {                // ---- Wih -> bf16 (prescaled), bias fold
        int local = bid - 17408;
        int dir = local / 1280, blk = local - dir * 1280;
        int idx = blk * 256 + tid;
        if (idx < FH * KP) {
            int row = idx / KP, k = idx - row * KP;
            float gsc = ((row >> 8) == 2) ? 2.0f * L2E : L2E;
            WihB[(size_t)dir * FH * KP + idx] =
                (k < 300) ? f2bf(Wih.p[dir][row * 300 + k] * gsc) : (u16)0;
        }
        if (idx < FH) {
            float gsc = ((idx >> 8) == 2) ? 2.0f * L2E : L2E;
            biasB[dir * FH + idx] = (bih.p[dir][idx] + bhh.p[dir][idx]) * gsc;
        }
    } else {                                 // ---- Whh -> i8 row-scaled (prescaled wdq)
        int local = bid - 22528;
        int w = tid >> 6, lane = tid & 63;
        int pair = local * 4 + w;
        int dir = pair >> 10, row = pair & 1023;
        const float* src = Whh.p[dir] + (size_t)row * HH;
        float m = 0.0f;
        for (int k = lane; k < HH; k += 64) m = fmaxf(m, fabsf(src[k]));
        for (int off = 32; off; off >>= 1) m = fmaxf(m, __shfl_down(m, off));
        m = __shfl(m, 0);
        float qs = (m > 0.0f) ? 127.0f / m : 0.0f;
        char* dst = Wq + (size_t)dir * FH * HH + (size_t)row * HH;
        for (int k = lane; k < HH; k += 64) dst[k] = (char)(int)rintf(src[k] * qs);
        if (lane == 0) {
            float gsc = ((row >> 8) == 2) ? 2.0f * L2E : L2E;
            wdq[dir * FH + row] = (m > 0.0f) ? m / (127.0f * 127.0f) * gsc : 0.0f;
        }
    }
}

// ---------------------------------------------------------------- fused input GEMM
// bid<4096: sen (M=16384, dirs 0,1, T=128).  bid>=4096: tgt (M=1024, dirs 2,3, T=8).
// 128-row m-tile x {16 units x 4 gates} per 256-thr block: the 64-row B panel staged
// once in LDS serves 128 A-rows (B-staging traffic and per-MFMA LDS reads halved vs
// the R5/R6 64-row tile). Barrier-free K-loop, XCD swizzle for L2 locality.
// Epilogue: lane holds all 4 gates of unit u0+r => one contiguous 8B u16x4 store into
// TIME-MAJOR G [t][b][unit*4+gate].
__global__ __launch_bounds__(256) void input_gemm_kernel(
    const u16* __restrict__ Xs, const u16* __restrict__ Xt,
    const u16* __restrict__ WihB, const float* __restrict__ biasB,
    u16* __restrict__ Gs, u16* __restrict__ Gt)
{
    __shared__ u16 Bs[64][KPL];

    int bid = blockIdx.x;
    const u16* X; const u16* W; const float* bias; u16* G;
    int lbid, nwg, tsh;
    if (bid < 4096) { lbid = bid;        nwg = 4096; tsh = 7;
                      X = Xs; W = WihB;                         bias = biasB;          G = Gs; }
    else            { lbid = bid - 4096; nwg = 256;  tsh = 3;
                      X = Xt; W = WihB + (size_t)2 * FH * KP;   bias = biasB + 2 * FH; G = Gt; }

    int cpx = nwg >> 3;
    int wid = (lbid & 7) * cpx + (lbid >> 3);
    int nblk = wid & 31;                       // 2 dirs x 16 unit-tiles
    int mblk = wid >> 5;
    int dirb = nblk >> 4;
    int u0   = (nblk & 15) * 16;
    size_t dirStride = (size_t)(tsh == 7 ? 16384 : 1024) * FH;

    int tid = threadIdx.x;
    int wave = tid >> 6, lane = tid & 63;
    int r = lane & 15, quad = lane >> 4;
    int m0 = mblk * 128 + wave * 32;           // wave covers 32 m-rows (2 subtiles)

    // ---- stage B panel: rows j*16+rr = W[dirb*1024 + j*256 + u0 + rr], full K=320
#pragma unroll
    for (int it = 0; it < 10; ++it) {
        int idx = it * 256 + tid;
        int row = idx / 40, cc = idx - row * 40;
        int j = row >> 4, rr = row & 15;
        bf16x8 v = *(const bf16x8*)(W + ((size_t)dirb * FH + j * 256 + u0 + rr) * KP + cc * 8);
        *(bf16x8*)&Bs[row][cc * 8] = v;
    }
    __syncthreads();

    // ---- barrier-free K loop, 2 m-subtiles share each B fragment
    const u16* xr = X + (size_t)(m0 + r) * KP + quad * 8;
    f32x4 acc[2][4] = {};
#pragma unroll
    for (int k0 = 0; k0 < KP; k0 += 32) {
        bf16x8 a0 = *(const bf16x8*)(xr + k0);
        bf16x8 a1 = *(const bf16x8*)(xr + 16 * KP + k0);
#pragma unroll
        for (int j = 0; j < 4; ++j) {
            bf16x8 b = *(const bf16x8*)&Bs[j * 16 + r][k0 + quad * 8];
            acc[0][j] = __builtin_amdgcn_mfma_f32_16x16x32_bf16(a0, b, acc[0][j], 0, 0, 0);
            acc[1][j] = __builtin_amdgcn_mfma_f32_16x16x32_bf16(a1, b, acc[1][j], 0, 0, 0);
        }
    }

    // ---- epilogue: bias + bf16; one 8B store per (sub,reg) into time-major G
#pragma unroll
    for (int sub = 0; sub < 2; ++sub)
#pragma unroll
        for (int reg = 0; reg < 4; ++reg) {
            int m = m0 + sub * 16 + quad * 4 + reg;
            int b = m >> tsh, t = m & ((1 << tsh) - 1);
            int unit = u0 + r;
            u16x4 ov;
#pragma unroll
            for (int j = 0; j < 4; ++j)
                ov[j] = f2bf(acc[sub][j][reg] + bias[dirb * FH + j * 256 + unit]);
            *(u16x4*)(G + (size_t)dirb * dirStride + ((size_t)t * 128 + b) * FH + unit * 4) = ov;
        }
}

// ---------------------------------------------------------------- LSTM scan
// 32 WGs x 1024 thr (16 waves; 4 waves/SIMD). dir = bx>>3, batch chunk = (bx&7)*16.
// Wave w owns units [w*16,w*16+16) x 4 gates; Bq[4][4] i32x4 = 64 regs/lane (AGPR),
// mfma_i32_16x16x64_i8 (16/step/wave). Gates exp2-prescaled. ONE barrier/step,
// VMEM software-pipelined one full step (gv(s+1) prefetch + h(s-1) store at step top).
// NEW (R7): G and H are both TIME-MAJOR => per-step address work collapses to 4 pointer
// increments with a uniform stride (+-128*FH / +-128*512, sign = direction), reg
// dimension folded into 13-bit immediate offsets. (R6's t = rev ? T-1-s : s select
// blocked compiler strength-reduction: full 64-bit recompute for 8 VMEM ops per step.)
// Final prefetch intentionally reads one step past [0,T): lands in the adjacent dir's
// region of the same workspace buffer (in-bounds, value unused).
__global__ __launch_bounds__(1024, 1) void lstm_scan_kernel(
    const char*  __restrict__ WqB,   // [4][1024][256] i8
    const float* __restrict__ wdq,   // [4][1024] dequant scales (prescaled)
    const u16*   __restrict__ Gs,    // [2][128t][128b][1024] bf16
    const u16*   __restrict__ Gt,    // [2][8t][128b][1024] bf16
    float* __restrict__ senH,        // [128t][128b][512]  TIME-MAJOR
    float* __restrict__ tgtH)        // [8t][128b][512]    TIME-MAJOR
{
    const int bx  = blockIdx.x;
    const int dir = bx >> 3;
    const int b0  = (bx & 7) << 4;
    const int T   = (dir < 2) ? 128 : 8;
    const int rev = dir & 1;

    const char* Wq = WqB + (size_t)dir * FH * HH;
    const u16*  G  = (dir < 2) ? (Gs + (size_t)dir * 16384 * FH)
                               : (Gt + (size_t)(dir - 2) * 1024 * FH);
    float* Hout = (dir < 2) ? senH : tgtH;
    const int hofs = rev ? 256 : 0;

    const int tid  = threadIdx.x;
    const int w    = tid >> 6, lane = tid & 63;
    const int r    = lane & 15, quad = lane >> 4;
    const int u    = w * 16 + r;     // this lane's unit

    __shared__ __align__(16) char hb8[2][16][272]; // h as i8, double-buffered

    // ---- Whh i8 B-frags into registers (persist across all steps)
    i32x4 Bq[4][4];
    float dqv[4];
#pragma unroll
    for (int g = 0; g < 4; ++g) {
        int row = g * 256 + u;
        dqv[g] = wdq[dir * FH + row];
#pragma unroll
        for (int kt = 0; kt < 4; ++kt)
            Bq[g][kt] = *(const i32x4*)(Wq + ((size_t)row << 8) + kt * 64 + quad * 16);
    }

    // ---- zero h(-1)
    for (int i = tid; i < 2 * 16 * 272; i += 1024) (&hb8[0][0][0])[i] = 0;
    __syncthreads();

    float c[4] = {};      // cell state per batch-row reg
    float hreg[4] = {};   // h(s-1), stored to Hout one step late

    // ---- marching pointers (uniform stride for all dirs; sign = direction)
    const int t0 = rev ? (T - 1) : 0;
    const ptrdiff_t gstep = rev ? -(ptrdiff_t)(128 * FH) : (ptrdiff_t)(128 * FH);
    const ptrdiff_t hstep = rev ? -(ptrdiff_t)(128 * 512) : (ptrdiff_t)(128 * 512);
    const u16* gp0 = G + ((size_t)t0 * 128 + b0 + quad * 4) * FH + u * 4;  // regs 0,1
    const u16* gp2 = gp0 + 2 * (size_t)FH;                                  // regs 2,3
    float* hp0 = Hout + ((size_t)t0 * 128 + b0 + quad * 4) * 512 + hofs + u;
    float* hp2 = hp0 + 2 * 512;

    // ---- prologue: pregates for step 0; advance g-pointers to step 1
    s16x4 gvA[4], gvB[4];
    gvA[0] = *(const s16x4*)(gp0);
    gvA[1] = *(const s16x4*)(gp0 + FH);
    gvA[2] = *(const s16x4*)(gp2);
    gvA[3] = *(const s16x4*)(gp2 + FH);
    gp0 += gstep; gp2 += gstep;

    // One step: prefetch gv(next) + store h(prev) FIRST (retire under MFMA+gates),
    // then MFMA from hb8[cur], then gates -> hreg + hb8[cur^1], then barrier.
    auto body = [&](int cur, s16x4 (&gvU)[4], s16x4 (&gvP)[4], int doStore) {
        gvP[0] = *(const s16x4*)(gp0);
        gvP[1] = *(const s16x4*)(gp0 + FH);
        gvP[2] = *(const s16x4*)(gp2);
        gvP[3] = *(const s16x4*)(gp2 + FH);
        gp0 += gstep; gp2 += gstep;
        if (doStore) {
            hp0[0] = hreg[0]; hp0[512] = hreg[1];
            hp2[0] = hreg[2]; hp2[512] = hreg[3];
            hp0 += hstep; hp2 += hstep;
        }

        i32x4 acc[4] = {};   // per gate
#pragma unroll
        for (int kt = 0; kt < 4; ++kt) {
            i32x4 a = *(const i32x4*)&hb8[cur][r][kt * 64 + quad * 16];
#pragma unroll
            for (int g = 0; g < 4; ++g)
                acc[g] = __builtin_amdgcn_mfma_i32_16x16x64_i8(a, Bq[g][kt], acc[g], 0, 0, 0);
        }

#pragma unroll
        for (int reg = 0; reg < 4; ++reg) {
            int bb = quad * 4 + reg;
            float pi = (float)acc[0][reg] * dqv[0] + bf2f((u16)gvU[reg].x);
            float pf = (float)acc[1][reg] * dqv[1] + bf2f((u16)gvU[reg].y);
            float pg = (float)acc[2][reg] * dqv[2] + bf2f((u16)gvU[reg].z);
            float po = (float)acc[3][reg] * dqv[3] + bf2f((u16)gvU[reg].w);
            float ig = sigm2(pi), fg = sigm2(pf), gg = tanh2(pg), og = sigm2(po);
            float cn = fg * c[reg] + ig * gg;
            c[reg] = cn;
            float hn = og * tanh2(cn * (2.0f * L2E));
            hb8[cur ^ 1][bb][u] = (char)(int)rintf(hn * 127.0f);
            hreg[reg] = hn;
        }
        __syncthreads();   // h(s) visible; gv prefetch + Hout store retired by now
    };

    for (int s2 = 0; s2 < T; s2 += 2) {
        body(0, gvA, gvB, s2 > 0);   // even step: reads hb8[0], writes hb8[1]
        body(1, gvB, gvA, 1);        // odd step:  reads hb8[1], writes hb8[0]
    }

    // ---- epilogue: store h(T-1) (hp now points at t = T-1's slot)
    hp0[0] = hreg[0]; hp0[512] = hreg[1];
    hp2[0] = hreg[2]; hp2[512] = hreg[3];
}

// ---------------------------------------------------------------- attention + head
// Reads TIME-MAJOR senH/tgtH: row (b,s) lives at ((s*128)+b)*512.
__global__ __launch_bounds__(256) void attn_out_kernel(
    const float* __restrict__ senH, const float* __restrict__ tgtH,
    const float* __restrict__ Wout, const float* __restrict__ bout,
    float* __restrict__ out)
{
    int b = blockIdx.x, tid = threadIdx.x;
    __shared__ float tg[8][512];
    __shared__ float Am[128][9];
    __shared__ float rowm[128][9];
    __shared__ float mcol[8], csum[8], rvec[8], attn[128], score[512], lg[3];

    for (int i = tid; i < 4096; i += 256) {
        int t = i >> 9, h = i & 511;
        tg[t][h] = tgtH[((size_t)t * 128 + b) * 512 + h];
    }
    __syncthreads();

    {   // A[s][t] = sen_h[b,s,:] . tgt_h[b,t,:]
        int s = tid >> 1, t0 = (tid & 1) * 4;
        const float* sr = senH + ((size_t)s * 128 + b) * 512;
        float d0 = 0, d1 = 0, d2 = 0, d3 = 0;
        for (int h = 0; h < 512; ++h) {
            float x = sr[h];
            d0 += x * tg[t0 + 0][h]; d1 += x * tg[t0 + 1][h];
            d2 += x * tg[t0 + 2][h]; d3 += x * tg[t0 + 3][h];
        }
        Am[s][t0 + 0] = d0; Am[s][t0 + 1] = d1; Am[s][t0 + 2] = d2; Am[s][t0 + 3] = d3;
    }
    __syncthreads();

    if (tid < 8) {  // col-softmax stats over s, per t
        float m = -1e30f;
        for (int s = 0; s < 128; ++s) m = fmaxf(m, Am[s][tid]);
        float sum = 0;
        for (int s = 0; s < 128; ++s) sum += __expf(Am[s][tid] - m);
        mcol[tid] = m; csum[tid] = sum;
    }
    if (tid >= 64 && tid < 192) {  // row softmax per s
        int s = tid - 64;
        float m = -1e30f;
        for (int t = 0; t < 8; ++t) m = fmaxf(m, Am[s][t]);
        float e[8], sum = 0;
        for (int t = 0; t < 8; ++t) { e[t] = __expf(Am[s][t] - m); sum += e[t]; }
        float inv = __builtin_amdgcn_rcpf(sum);
        for (int t = 0; t < 8; ++t) rowm[s][t] = e[t] * inv;
    }
    __syncthreads();
    if (tid < 8) {
        float sum = 0;
        for (int s = 0; s < 128; ++s) sum += rowm[s][tid];
        rvec[tid] = sum * (1.0f / 128.0f);
    }
    __syncthreads();
    if (tid < 128) {
        float a = 0;
        for (int t = 0; t < 8; ++t)
            a += __expf(Am[tid][t] - mcol[t]) / csum[t] * rvec[t];
        attn[tid] = a;
    }
    __syncthreads();
    for (int h = tid; h < 512; h += 256) {
        float acc = 0;
        const float* sp = senH + b * 512 + h;
        for (int s = 0; s < 128; ++s) acc += attn[s] * sp[(size_t)s * 128 * 512];
        score[h] = acc;
    }
    __syncthreads();
    if (tid < 3) {
        float acc = bout[tid];
        const float* wr = Wout + tid * 512;
        for (int h = 0; h < 512; ++h) acc += score[h] * wr[h];
        lg[tid] = acc;
    }
    __syncthreads();
    if (tid == 0) {
        float m = fmaxf(lg[0], fmaxf(lg[1], lg[2]));
        float e0 = __expf(lg[0] - m), e1 = __expf(lg[1] - m), e2 = __expf(lg[2] - m);
        float inv = 1.0f / (e0 + e1 + e2);
        out[b * 3 + 0] = e0 * inv; out[b * 3 + 1] = e1 * inv; out[b * 3 + 2] = e2 * inv;
    }
}

// ---------------------------------------------------------------- launch
extern "C" void kernel_launch(void* const* d_in, const int* in_sizes, int n_in,
                              void* d_out, int out_size, void* d_ws, size_t ws_size,
                              hipStream_t stream)
{
    const int*   sen = (const int*)d_in[0];
    const int*   tgt = (const int*)d_in[1];
    const float* emb = (const float*)d_in[2];
    Ptr4 Wih = {{(const float*)d_in[3],  (const float*)d_in[7],
                 (const float*)d_in[11], (const float*)d_in[15]}};
    Ptr4 Whh = {{(const float*)d_in[4],  (const float*)d_in[8],
                 (const float*)d_in[12], (const float*)d_in[16]}};
    Ptr4 bih = {{(const float*)d_in[5],  (const float*)d_in[9],
                 (const float*)d_in[13], (const float*)d_in[17]}};
    Ptr4 bhh = {{(const float*)d_in[6],  (const float*)d_in[10],
                 (const float*)d_in[14], (const float*)d_in[18]}};
    const float* Wout = (const float*)d_in[19];
    const float* bout = (const float*)d_in[20];
    float* out = (float*)d_out;

    char* ws = (char*)d_ws;
    size_t off = 0;
    auto alloc = [&](size_t bytes) -> void* {
        void* p = ws + off; off += (bytes + 255) & ~(size_t)255; return p;
    };
    u16*   Xs    = (u16*)alloc((size_t)16384 * KP * 2);
    u16*   Xt    = (u16*)alloc((size_t)1024 * KP * 2);
    u16*   WihB  = (u16*)alloc((size_t)4 * FH * KP * 2);
    char*  WqB   = (char*)alloc((size_t)4 * FH * HH);
    float* wdq   = (float*)alloc((size_t)4 * FH * 4);
    float* biasB = (float*)alloc((size_t)4 * FH * 4);
    u16*   Gs    = (u16*)alloc((size_t)2 * 16384 * FH * 2);
    u16*   Gt    = (u16*)alloc((size_t)2 * 1024 * FH * 2);
    float* senH  = (float*)alloc((size_t)128 * 128 * 512 * 4);
    float* tgtH  = (float*)alloc((size_t)128 * 8 * 512 * 4);
    (void)ws_size; (void)in_sizes; (void)n_in; (void)out_size;

    pre_kernel<<<23552, 256, 0, stream>>>(sen, tgt, emb, Wih, Whh, bih, bhh,
                                          Xs, Xt, WihB, biasB, WqB, wdq);
    input_gemm_kernel<<<4352, 256, 0, stream>>>(Xs, Xt, WihB, biasB, Gs, Gt);
    lstm_scan_kernel<<<32, 1024, 0, stream>>>(WqB, wdq, Gs, Gt, senH, tgtH);
    attn_out_kernel<<<128, 256, 0, stream>>>(senH, tgtH, Wout, bout, out);
}